// Round 12
// baseline (212.293 us; speedup 1.0000x reference)
//
#include <hip/hip_runtime.h>
#include <hip/hip_bf16.h>

// Problem constants (fixed by the reference)
#define NN 8192   // nodes per side
#define ED 128    // embedding dim E
#define DD 64     // attention dim D
#define KK 32     // neighbors per node
#define MM 4      // metapaths

typedef __attribute__((ext_vector_type(8))) short short8;   // 8 bf16 (4 VGPRs)
typedef __attribute__((ext_vector_type(4))) float f32x4;    // MFMA acc

// Fast tanh: tanh(x) = 1 - 2/(exp(2x)+1). Saturates correctly at +/-1.
__device__ __forceinline__ float ftanh(float x)
{
    const float e = __expf(2.0f * x);
    return fmaf(-2.0f, __builtin_amdgcn_rcpf(e + 1.0f), 1.0f);
}

__device__ __forceinline__ unsigned short f2bf(float x)
{
    __hip_bfloat16 b = __float2bfloat16(x);
    return *reinterpret_cast<unsigned short*>(&b);
}
__device__ __forceinline__ float bflo(unsigned int u) { return __uint_as_float(u << 16); }
__device__ __forceinline__ float bfhi(unsigned int u) { return __uint_as_float(u & 0xFFFF0000u); }
__device__ __forceinline__ float readlane_f(float v, int lane)
{
    return __uint_as_float(__builtin_amdgcn_readlane(__float_as_uint(v), lane));
}

// -------------------------------------------------------------------------
// convert2: f32 -> bf16 for user (y=0) and product (y=1). 4 elems/thread.
// grid: (NN*ED/4/256, 2)
// -------------------------------------------------------------------------
__global__ __launch_bounds__(256) void convert2_kernel(
    const float* __restrict__ inA, unsigned short* __restrict__ outA,
    const float* __restrict__ inB, unsigned short* __restrict__ outB)
{
    const float* in = blockIdx.y ? inB : inA;
    unsigned short* out = blockIdx.y ? outB : outA;
    const int i = blockIdx.x * 256 + threadIdx.x;
    const float4 v = ((const float4*)in)[i];
    uint2 o;
    o.x = (unsigned int)f2bf(v.x) | ((unsigned int)f2bf(v.y) << 16);
    o.y = (unsigned int)f2bf(v.z) | ((unsigned int)f2bf(v.w) << 16);
    ((uint2*)out)[i] = o;
}

// -------------------------------------------------------------------------
// transpose3: W f32 [S,ED,DD] -> Wt bf16 [S,DD,ED] for V (y=0), W_p (y=1),
// W_q (y=2). S = 2*MM slices. grid: (2*MM*ED*DD/256, 3)
// -------------------------------------------------------------------------
__global__ __launch_bounds__(256) void transpose3_kernel(
    const float* __restrict__ inV, unsigned short* __restrict__ outV,
    const float* __restrict__ inP, unsigned short* __restrict__ outP,
    const float* __restrict__ inQ, unsigned short* __restrict__ outQ)
{
    const float* in = (blockIdx.y == 0) ? inV : (blockIdx.y == 1) ? inP : inQ;
    unsigned short* out = (blockIdx.y == 0) ? outV : (blockIdx.y == 1) ? outP : outQ;
    const int gid = blockIdx.x * 256 + threadIdx.x;
    const int s   = gid >> 13;          // ED*DD = 8192
    const int rem = gid & 8191;
    const int e   = rem >> 6;
    const int d   = rem & 63;
    out[((size_t)s * DD + d) * ED + e] = f2bf(in[gid]);
}

// -------------------------------------------------------------------------
// proj2_mfma: both per-phase projections in one launch (blockIdx.z):
//   z=0: S  = emb0 @ Wt0 + Bias0 -> f32 outF0
//   z=1: Pn = emb1 @ Wt1         -> bf16 outB1
// MFMA 16x16x32 bf16; wave = 16 rows x 64 cols. grid: (NN/64, MM, 2).
// -------------------------------------------------------------------------
__global__ __launch_bounds__(256) void proj2_mfma(
    const unsigned short* __restrict__ emb0,  // [NN,ED] bf16
    const unsigned short* __restrict__ Wt0,   // [MM,DD,ED] bf16
    const float* __restrict__ Bias0,          // [MM,DD]
    float* __restrict__ outF0,                // [MM,NN,DD] f32
    const unsigned short* __restrict__ emb1,  // [NN,ED] bf16
    const unsigned short* __restrict__ Wt1,   // [MM,DD,ED] bf16
    unsigned short* __restrict__ outB1)       // [MM,NN,DD] bf16
{
    const int z    = blockIdx.z;
    const int m    = blockIdx.y;
    const int tid  = threadIdx.x;
    const int wave = tid >> 6;
    const int lane = tid & 63;
    const int nrow = lane & 15;
    const int quad = lane >> 4;
    const int r0   = blockIdx.x * 64 + wave * 16;

    const unsigned short* embB = z ? emb1 : emb0;
    const unsigned short* WtB  = z ? Wt1 : Wt0;

    const short8* A8 = (const short8*)(embB + (size_t)(r0 + nrow) * ED);
    const short8* B8 = (const short8*)(WtB + (size_t)m * DD * ED);

    f32x4 acc0 = {0.f, 0.f, 0.f, 0.f};
    f32x4 acc1 = {0.f, 0.f, 0.f, 0.f};
    f32x4 acc2 = {0.f, 0.f, 0.f, 0.f};
    f32x4 acc3 = {0.f, 0.f, 0.f, 0.f};

    #pragma unroll
    for (int kq = 0; kq < 4; ++kq) {
        const short8 a = A8[kq * 4 + quad];
        const short8 b0 = B8[(0 * 16 + nrow) * 16 + kq * 4 + quad];
        const short8 b1 = B8[(1 * 16 + nrow) * 16 + kq * 4 + quad];
        const short8 b2 = B8[(2 * 16 + nrow) * 16 + kq * 4 + quad];
        const short8 b3 = B8[(3 * 16 + nrow) * 16 + kq * 4 + quad];
        acc0 = __builtin_amdgcn_mfma_f32_16x16x32_bf16(a, b0, acc0, 0, 0, 0);
        acc1 = __builtin_amdgcn_mfma_f32_16x16x32_bf16(a, b1, acc1, 0, 0, 0);
        acc2 = __builtin_amdgcn_mfma_f32_16x16x32_bf16(a, b2, acc2, 0, 0, 0);
        acc3 = __builtin_amdgcn_mfma_f32_16x16x32_bf16(a, b3, acc3, 0, 0, 0);
    }

    f32x4 accs[4] = {acc0, acc1, acc2, acc3};
    if (z == 0) {
        #pragma unroll
        for (int t = 0; t < 4; ++t) {
            const int d = t * 16 + nrow;
            const float bv = Bias0[m * DD + d];
            #pragma unroll
            for (int reg = 0; reg < 4; ++reg) {
                const int r = r0 + quad * 4 + reg;
                outF0[((size_t)m * NN + r) * DD + d] = accs[t][reg] + bv;
            }
        }
    } else {
        #pragma unroll
        for (int t = 0; t < 4; ++t) {
            const int d = t * 16 + nrow;
            #pragma unroll
            for (int reg = 0; reg < 4; ++reg) {
                const int r = r0 + quad * 4 + reg;
                outB1[((size_t)m * NN + r) * DD + d] = f2bf(accs[t][reg]);
            }
        }
    }
}

// -------------------------------------------------------------------------
// attn_kernel: 4 waves/block, one (m,j) per wave, zero LDS.
// MLP-restructured: all gather loads issued in bulk before their consumers
// so the compiler can keep 8 (scores) / 32 (H-agg) loads in flight instead
// of serial load->use round-trips (R11 had VGPR_Count=24 -> serial chains).
// grid: (NN/4, MM), block 256.
// -------------------------------------------------------------------------
__global__ __launch_bounds__(256) void attn_kernel(
    const float* __restrict__ src,             // [NN,ED] f32
    const unsigned short* __restrict__ otherB, // [NN,ED] bf16
    const int*   __restrict__ nbrs,            // [MM,NN,KK]
    const float* __restrict__ S,               // [MM,NN,DD] f32
    const unsigned short* __restrict__ PnB,    // [MM,NN,DD] bf16
    const float* __restrict__ Xv,              // [MM,DD] f32
    unsigned short* __restrict__ HoutB)        // [MM,NN,ED] bf16
{
    const int m    = blockIdx.y;
    const int tid  = threadIdx.x;
    const int w    = tid >> 6;
    const int lane = tid & 63;
    const int j    = blockIdx.x * 4 + w;

    const int kg = lane >> 4;        // which k within each quad (0..3)
    const int dq = lane & 15;        // d quad index (d0 = 4*dq)

    int idxreg = 0;
    if (lane < KK) idxreg = nbrs[((size_t)m * NN + j) * KK + lane];

    const float4 S4 = *(const float4*)(S + ((size_t)m * NN + j) * DD + dq * 4);
    const float4 X4 = *(const float4*)(Xv + (size_t)m * DD + dq * 4);
    // src row prefetch (consumed in H-agg, issued early)
    const float2 h0 = ((const float2*)(src + (size_t)j * ED))[lane];

    // ---- scores: prefetch all 8 Pn rows, then the tanh chains
    uint2 pv[8];
    #pragma unroll
    for (int i = 0; i < 8; ++i) {
        const int jk = __shfl(idxreg, i * 4 + kg, 64);
        pv[i] = ((const uint2*)(PnB + ((size_t)m * NN + jk) * DD))[dq];
    }
    float e_arr[8];  // row kg handles k = i*4 + kg
    #pragma unroll
    for (int i = 0; i < 8; ++i) {
        float p = ftanh(S4.x + bflo(pv[i].x)) * X4.x;
        p = fmaf(ftanh(S4.y + bfhi(pv[i].x)), X4.y, p);
        p = fmaf(ftanh(S4.z + bflo(pv[i].y)), X4.z, p);
        p = fmaf(ftanh(S4.w + bfhi(pv[i].y)), X4.w, p);
        p += __shfl_xor(p, 1, 64);
        p += __shfl_xor(p, 2, 64);
        p += __shfl_xor(p, 4, 64);
        p += __shfl_xor(p, 8, 64);
        e_arr[i] = p;
    }

    // ---- H-agg gathers: issue ALL 32 row loads before the softmax math so
    // they overlap it (addresses are wave-uniform -> readlane/saddr form).
    unsigned int ov[32];
    #pragma unroll
    for (int k = 0; k < KK; ++k) {
        const int jk = __builtin_amdgcn_readlane(idxreg, k);
        ov[k] = ((const unsigned int*)(otherB + (size_t)jk * ED))[lane];
    }

    // ---- softmax over the 32 k with the reference's full-axis baseline
    const float baseline = (m == 0) ? -1e-9f : (1.0f / (float)NN);
    float mx = e_arr[0];
    #pragma unroll
    for (int i = 1; i < 8; ++i) mx = fmaxf(mx, e_arr[i]);
    mx = fmaxf(mx, __shfl_xor(mx, 16, 64));
    mx = fmaxf(mx, __shfl_xor(mx, 32, 64));
    mx = fmaxf(mx, baseline);
    float sum = 0.0f;
    #pragma unroll
    for (int i = 0; i < 8; ++i) { e_arr[i] = __expf(e_arr[i] - mx); sum += e_arr[i]; }
    sum += __shfl_xor(sum, 16, 64);
    sum += __shfl_xor(sum, 32, 64);
    const float inv_denom =
        __builtin_amdgcn_rcpf(sum + (float)(NN - KK) * __expf(baseline - mx));
    #pragma unroll
    for (int i = 0; i < 8; ++i) e_arr[i] *= inv_denom;   // A for k = i*4+kg

    // ---- H aggregation: lane covers elements {2*lane, 2*lane+1}
    float2 h = h0;
    #pragma unroll
    for (int k = 0; k < KK; ++k) {
        const float a = readlane_f(e_arr[k >> 2], (k & 3) * 16);
        h.x = fmaf(a, bflo(ov[k]), h.x);
        h.y = fmaf(a, bfhi(ov[k]), h.y);
    }
    const unsigned int hu =
        (unsigned int)f2bf(h.x) | ((unsigned int)f2bf(h.y) << 16);
    ((unsigned int*)(HoutB + ((size_t)m * NN + j) * ED))[lane] = hu;
}

// -------------------------------------------------------------------------
// sem_mfma: per-block beta partials, direct slot write (no atomics).
// grid: (NN/64, MM), block 256.
// -------------------------------------------------------------------------
__global__ __launch_bounds__(256) void sem_mfma(
    const unsigned short* __restrict__ HB,    // [MM,NN,ED] bf16
    const unsigned short* __restrict__ WqT,   // [MM,DD,ED] bf16
    const float* __restrict__ Bq,             // [MM,DD]
    const float* __restrict__ Qv,             // [MM,DD]
    float* __restrict__ bp)                   // [MM*128]
{
    const int m    = blockIdx.y;
    const int tid  = threadIdx.x;
    const int wave = tid >> 6;
    const int lane = tid & 63;
    const int nrow = lane & 15;
    const int quad = lane >> 4;
    const int r0   = blockIdx.x * 64 + wave * 16;

    __shared__ float red_sh[4];

    const short8* A8 = (const short8*)(HB + ((size_t)m * NN + r0 + nrow) * ED);
    const short8* B8 = (const short8*)(WqT + (size_t)m * DD * ED);

    f32x4 acc0 = {0.f, 0.f, 0.f, 0.f};
    f32x4 acc1 = {0.f, 0.f, 0.f, 0.f};
    f32x4 acc2 = {0.f, 0.f, 0.f, 0.f};
    f32x4 acc3 = {0.f, 0.f, 0.f, 0.f};

    #pragma unroll
    for (int kq = 0; kq < 4; ++kq) {
        const short8 a = A8[kq * 4 + quad];
        const short8 b0 = B8[(0 * 16 + nrow) * 16 + kq * 4 + quad];
        const short8 b1 = B8[(1 * 16 + nrow) * 16 + kq * 4 + quad];
        const short8 b2 = B8[(2 * 16 + nrow) * 16 + kq * 4 + quad];
        const short8 b3 = B8[(3 * 16 + nrow) * 16 + kq * 4 + quad];
        acc0 = __builtin_amdgcn_mfma_f32_16x16x32_bf16(a, b0, acc0, 0, 0, 0);
        acc1 = __builtin_amdgcn_mfma_f32_16x16x32_bf16(a, b1, acc1, 0, 0, 0);
        acc2 = __builtin_amdgcn_mfma_f32_16x16x32_bf16(a, b2, acc2, 0, 0, 0);
        acc3 = __builtin_amdgcn_mfma_f32_16x16x32_bf16(a, b3, acc3, 0, 0, 0);
    }

    f32x4 accs[4] = {acc0, acc1, acc2, acc3};
    float part = 0.0f;
    #pragma unroll
    for (int t = 0; t < 4; ++t) {
        const int d = t * 16 + nrow;
        const float bq = Bq[m * DD + d];
        const float qv = Qv[m * DD + d];
        #pragma unroll
        for (int reg = 0; reg < 4; ++reg)
            part = fmaf(ftanh(accs[t][reg] + bq), qv, part);
    }
    #pragma unroll
    for (int off = 32; off; off >>= 1) part += __shfl_xor(part, off, 64);
    if (lane == 0) red_sh[wave] = part;
    __syncthreads();
    if (tid == 0)
        bp[m * 128 + blockIdx.x] =
            (red_sh[0] + red_sh[1]) + (red_sh[2] + red_sh[3]);
}

// -------------------------------------------------------------------------
// beta_reduce: 512 slots [m*128+i] -> beta softmax -> bw[4]. 1 wave.
// -------------------------------------------------------------------------
__global__ void beta_reduce(const float* __restrict__ bp, float* __restrict__ bw)
{
    const int lane = threadIdx.x;     // 0..63
    const int m = lane >> 4, t = lane & 15;
    float s = 0.0f;
    #pragma unroll
    for (int i = 0; i < 8; ++i)
        s += bp[m * 128 + t + i * 16];
    s += __shfl_xor(s, 1, 64);
    s += __shfl_xor(s, 2, 64);
    s += __shfl_xor(s, 4, 64);
    s += __shfl_xor(s, 8, 64);
    const float v = s * (1.0f / (float)NN);
    float mx = v;
    mx = fmaxf(mx, __shfl_xor(mx, 16, 64));
    mx = fmaxf(mx, __shfl_xor(mx, 32, 64));
    const float e = expf(v - mx);
    float es = e;
    es += __shfl_xor(es, 16, 64);
    es += __shfl_xor(es, 32, 64);
    if (t == 0) bw[m] = e / es;
}

// -------------------------------------------------------------------------
// combine: out = sum_m bw[m]*H[m] from bf16 H; f32 out (+bf16 for phase-1).
// -------------------------------------------------------------------------
__global__ __launch_bounds__(256) void combine_kernel(
    const unsigned short* __restrict__ HB,  // [MM,NN,ED] bf16
    const float* __restrict__ bw,           // [4] softmaxed
    float* __restrict__ outp,               // [NN,ED] f32
    unsigned short* __restrict__ outB)      // [NN,ED] bf16 or nullptr
{
    const int i = blockIdx.x * 256 + threadIdx.x;   // uint2 (4-elem) index
    const size_t st = (size_t)NN * ED / 4;
    const uint2* h = (const uint2*)HB;
    float r0 = 0.f, r1 = 0.f, r2 = 0.f, r3 = 0.f;
    #pragma unroll
    for (int s = 0; s < MM; ++s) {
        const float b = bw[s];
        const uint2 v = h[s * st + i];
        r0 = fmaf(b, bflo(v.x), r0);
        r1 = fmaf(b, bfhi(v.x), r1);
        r2 = fmaf(b, bflo(v.y), r2);
        r3 = fmaf(b, bfhi(v.y), r3);
    }
    float4 o; o.x = r0; o.y = r1; o.z = r2; o.w = r3;
    ((float4*)outp)[i] = o;
    if (outB) {
        uint2 ob;
        ob.x = (unsigned int)f2bf(r0) | ((unsigned int)f2bf(r1) << 16);
        ob.y = (unsigned int)f2bf(r2) | ((unsigned int)f2bf(r3) << 16);
        ((uint2*)outB)[i] = ob;
    }
}

// -------------------------------------------------------------------------
extern "C" void kernel_launch(void* const* d_in, const int* in_sizes, int n_in,
                              void* d_out, int out_size, void* d_ws, size_t ws_size,
                              hipStream_t stream)
{
    // dict order: user, product, V, X, W_p, B_p, W_q, B_q, Q, user_nbrs, product_nbrs
    const float* user    = (const float*)d_in[0];
    const float* product = (const float*)d_in[1];
    const float* V   = (const float*)d_in[2];
    const float* X   = (const float*)d_in[3];
    const float* W_p = (const float*)d_in[4];
    const float* B_p = (const float*)d_in[5];
    const float* W_q = (const float*)d_in[6];
    const float* B_q = (const float*)d_in[7];
    const float* Q   = (const float*)d_in[8];
    const int* user_nbrs    = (const int*)d_in[9];
    const int* product_nbrs = (const int*)d_in[10];

    float* out  = (float*)d_out;            // [2,NN,ED] f32
    float* out0 = out;
    float* out1 = out + (size_t)NN * ED;

    // workspace layout
    float* ws = (float*)d_ws;
    float* bp = ws;                               // 512 (pad 1024)
    float* bw = bp + 1024;                        // 16
    float* S  = bw + 16;                          // MM*NN*DD f32
    unsigned short* us = (unsigned short*)(S + (size_t)MM * NN * DD);
    unsigned short* PnB      = us;                             // MM*NN*DD
    unsigned short* HB       = PnB + (size_t)MM * NN * DD;     // MM*NN*ED
    unsigned short* userB    = HB + (size_t)MM * NN * ED;      // NN*ED
    unsigned short* productB = userB + (size_t)NN * ED;        // NN*ED
    unsigned short* oB       = productB + (size_t)NN * ED;     // NN*ED
    unsigned short* VT       = oB + (size_t)NN * ED;           // 2*MM*DD*ED
    unsigned short* PT       = VT + (size_t)2 * MM * DD * ED;
    unsigned short* QT       = PT + (size_t)2 * MM * DD * ED;

    const size_t MED = (size_t)MM * ED * DD;   // per-phase weight slice
    const size_t MD  = (size_t)MM * DD;

    const dim3 gM2(NN / 64, MM, 2);            // fused proj grid
    const dim3 gM(NN / 64, MM);                // sem grid
    const dim3 gA(NN / 4, MM);
    const int cBlocks = (NN * ED / 4) / 256;
    const int wN = 2 * MM * ED * DD;           // whole weight tensor elems

    // ---------------- prep: bf16 conversions & weight transposes ----------
    convert2_kernel<<<dim3(cBlocks, 2), 256, 0, stream>>>(user, userB,
                                                          product, productB);
    transpose3_kernel<<<dim3(wN / 256, 3), 256, 0, stream>>>(V, VT, W_p, PT,
                                                             W_q, QT);

    // ===================== phase 0: user side =====================
    {
        proj2_mfma<<<gM2, 256, 0, stream>>>(userB, VT, B_p, S,
                                            productB, PT, PnB);
        attn_kernel<<<gA, 256, 0, stream>>>(user, productB, user_nbrs,
                                            S, PnB, X, HB);
        sem_mfma<<<gM, 256, 0, stream>>>(HB, QT, B_q, Q, bp);
        beta_reduce<<<1, 64, 0, stream>>>(bp, bw);
        combine_kernel<<<cBlocks, 256, 0, stream>>>(HB, bw, out0, oB);
    }

    // ===================== phase 1: product side ==================
    // attends over the UPDATED user embeddings (= out0 / oB)
    {
        proj2_mfma<<<gM2, 256, 0, stream>>>(productB, VT + MED, B_p + MD, S,
                                            oB, PT + MED, PnB);
        attn_kernel<<<gA, 256, 0, stream>>>(product, oB, product_nbrs,
                                            S, PnB, X + MD, HB);
        sem_mfma<<<gM, 256, 0, stream>>>(HB, QT + MED, B_q + MD, Q + MD, bp);
        beta_reduce<<<1, 64, 0, stream>>>(bp, bw);
        combine_kernel<<<cBlocks, 256, 0, stream>>>(HB, bw, out1, nullptr);
    }
}

// Round 13
// 209.277 us; speedup vs baseline: 1.0144x; 1.0144x over previous
//
#include <hip/hip_runtime.h>
#include <hip/hip_bf16.h>

// Problem constants (fixed by the reference)
#define NN 8192   // nodes per side
#define ED 128    // embedding dim E
#define DD 64     // attention dim D
#define KK 32     // neighbors per node
#define MM 4      // metapaths

typedef __attribute__((ext_vector_type(8))) short short8;   // 8 bf16 (4 VGPRs)
typedef __attribute__((ext_vector_type(4))) float f32x4;    // MFMA acc

// Fast tanh: tanh(x) = 1 - 2/(exp(2x)+1). Saturates correctly at +/-1.
__device__ __forceinline__ float ftanh(float x)
{
    const float e = __expf(2.0f * x);
    return fmaf(-2.0f, __builtin_amdgcn_rcpf(e + 1.0f), 1.0f);
}

__device__ __forceinline__ unsigned short f2bf(float x)
{
    __hip_bfloat16 b = __float2bfloat16(x);
    return *reinterpret_cast<unsigned short*>(&b);
}
__device__ __forceinline__ float bflo(unsigned int u) { return __uint_as_float(u << 16); }
__device__ __forceinline__ float bfhi(unsigned int u) { return __uint_as_float(u & 0xFFFF0000u); }
__device__ __forceinline__ float readlane_f(float v, int lane)
{
    return __uint_as_float(__builtin_amdgcn_readlane(__float_as_uint(v), lane));
}

// -------------------------------------------------------------------------
// prep_kernel: one launch for all input reformatting.
//  y=0: user f32->bf16   y=1: product f32->bf16   (x < 1024, 4 elems/thr)
//  y=2/3/4: V/W_p/W_q f32 [S,ED,DD] -> bf16 [S,DD,ED]  (x < 256)
// grid: (1024, 5), block 256.
// -------------------------------------------------------------------------
__global__ __launch_bounds__(256) void prep_kernel(
    const float* __restrict__ user, unsigned short* __restrict__ userB,
    const float* __restrict__ product, unsigned short* __restrict__ productB,
    const float* __restrict__ V, unsigned short* __restrict__ VT,
    const float* __restrict__ Wp, unsigned short* __restrict__ PT,
    const float* __restrict__ Wq, unsigned short* __restrict__ QT)
{
    const int y = blockIdx.y;
    if (y < 2) {
        const float* in = y ? product : user;
        unsigned short* out = y ? productB : userB;
        const int i = blockIdx.x * 256 + threadIdx.x;
        const float4 v = ((const float4*)in)[i];
        uint2 o;
        o.x = (unsigned int)f2bf(v.x) | ((unsigned int)f2bf(v.y) << 16);
        o.y = (unsigned int)f2bf(v.z) | ((unsigned int)f2bf(v.w) << 16);
        ((uint2*)out)[i] = o;
    } else {
        if (blockIdx.x >= 256) return;
        const float* in = (y == 2) ? V : (y == 3) ? Wp : Wq;
        unsigned short* out = (y == 2) ? VT : (y == 3) ? PT : QT;
        const int gid = blockIdx.x * 256 + threadIdx.x;
        const int s   = gid >> 13;          // ED*DD = 8192
        const int rem = gid & 8191;
        const int e   = rem >> 6;
        const int d   = rem & 63;
        out[((size_t)s * DD + d) * ED + e] = f2bf(in[gid]);
    }
}

// -------------------------------------------------------------------------
// proj2_mfma: both per-phase projections in one launch (blockIdx.z):
//   z=0: S  = emb0 @ Wt0 + Bias0 -> f32 outF0
//   z=1: Pn = emb1 @ Wt1         -> bf16 outB1
// MFMA 16x16x32 bf16; wave = 16 rows x 64 cols. grid: (NN/64, MM, 2).
// -------------------------------------------------------------------------
__global__ __launch_bounds__(256) void proj2_mfma(
    const unsigned short* __restrict__ emb0,  // [NN,ED] bf16
    const unsigned short* __restrict__ Wt0,   // [MM,DD,ED] bf16
    const float* __restrict__ Bias0,          // [MM,DD]
    float* __restrict__ outF0,                // [MM,NN,DD] f32
    const unsigned short* __restrict__ emb1,  // [NN,ED] bf16
    const unsigned short* __restrict__ Wt1,   // [MM,DD,ED] bf16
    unsigned short* __restrict__ outB1)       // [MM,NN,DD] bf16
{
    const int z    = blockIdx.z;
    const int m    = blockIdx.y;
    const int tid  = threadIdx.x;
    const int wave = tid >> 6;
    const int lane = tid & 63;
    const int nrow = lane & 15;
    const int quad = lane >> 4;
    const int r0   = blockIdx.x * 64 + wave * 16;

    const unsigned short* embB = z ? emb1 : emb0;
    const unsigned short* WtB  = z ? Wt1 : Wt0;

    const short8* A8 = (const short8*)(embB + (size_t)(r0 + nrow) * ED);
    const short8* B8 = (const short8*)(WtB + (size_t)m * DD * ED);

    f32x4 acc0 = {0.f, 0.f, 0.f, 0.f};
    f32x4 acc1 = {0.f, 0.f, 0.f, 0.f};
    f32x4 acc2 = {0.f, 0.f, 0.f, 0.f};
    f32x4 acc3 = {0.f, 0.f, 0.f, 0.f};

    #pragma unroll
    for (int kq = 0; kq < 4; ++kq) {
        const short8 a = A8[kq * 4 + quad];
        const short8 b0 = B8[(0 * 16 + nrow) * 16 + kq * 4 + quad];
        const short8 b1 = B8[(1 * 16 + nrow) * 16 + kq * 4 + quad];
        const short8 b2 = B8[(2 * 16 + nrow) * 16 + kq * 4 + quad];
        const short8 b3 = B8[(3 * 16 + nrow) * 16 + kq * 4 + quad];
        acc0 = __builtin_amdgcn_mfma_f32_16x16x32_bf16(a, b0, acc0, 0, 0, 0);
        acc1 = __builtin_amdgcn_mfma_f32_16x16x32_bf16(a, b1, acc1, 0, 0, 0);
        acc2 = __builtin_amdgcn_mfma_f32_16x16x32_bf16(a, b2, acc2, 0, 0, 0);
        acc3 = __builtin_amdgcn_mfma_f32_16x16x32_bf16(a, b3, acc3, 0, 0, 0);
    }

    f32x4 accs[4] = {acc0, acc1, acc2, acc3};
    if (z == 0) {
        #pragma unroll
        for (int t = 0; t < 4; ++t) {
            const int d = t * 16 + nrow;
            const float bv = Bias0[m * DD + d];
            #pragma unroll
            for (int reg = 0; reg < 4; ++reg) {
                const int r = r0 + quad * 4 + reg;
                outF0[((size_t)m * NN + r) * DD + d] = accs[t][reg] + bv;
            }
        }
    } else {
        #pragma unroll
        for (int t = 0; t < 4; ++t) {
            const int d = t * 16 + nrow;
            #pragma unroll
            for (int reg = 0; reg < 4; ++reg) {
                const int r = r0 + quad * 4 + reg;
                outB1[((size_t)m * NN + r) * DD + d] = f2bf(accs[t][reg]);
            }
        }
    }
}

// -------------------------------------------------------------------------
// attn_kernel v4: 4 waves/block, TWO nodes (j0,j1) per wave — two fully
// independent dependency chains interleaved statement-by-statement to hide
// transcendental + gather latency (R12 showed the compiler re-sinks bulk
// prefetches; structural ILP can't be serialized). Neighbor ids: lanes 0-31
// hold j0's, lanes 32-63 hold j1's. grid: (NN/8, MM), block 256.
// -------------------------------------------------------------------------
__global__ __launch_bounds__(256) void attn_kernel(
    const float* __restrict__ src,             // [NN,ED] f32
    const unsigned short* __restrict__ otherB, // [NN,ED] bf16
    const int*   __restrict__ nbrs,            // [MM,NN,KK]
    const float* __restrict__ S,               // [MM,NN,DD] f32
    const unsigned short* __restrict__ PnB,    // [MM,NN,DD] bf16
    const float* __restrict__ Xv,              // [MM,DD] f32
    unsigned short* __restrict__ HoutB)        // [MM,NN,ED] bf16
{
    const int m    = blockIdx.y;
    const int tid  = threadIdx.x;
    const int w    = tid >> 6;
    const int lane = tid & 63;
    const int g    = blockIdx.x * 4 + w;   // wave id 0..4095
    const int j0   = g * 2;
    const int j1   = g * 2 + 1;

    const int kg = lane >> 4;        // which k within each quad (0..3)
    const int dq = lane & 15;        // d quad index (d0 = 4*dq)

    // neighbor ids: lanes 0-31 -> j0's k, lanes 32-63 -> j1's k
    const int jj = (lane < 32) ? j0 : j1;
    const int idxreg = nbrs[((size_t)m * NN + jj) * KK + (lane & 31)];

    const float4 S40 = *(const float4*)(S + ((size_t)m * NN + j0) * DD + dq * 4);
    const float4 S41 = *(const float4*)(S + ((size_t)m * NN + j1) * DD + dq * 4);
    const float4 X4  = *(const float4*)(Xv + (size_t)m * DD + dq * 4);
    const float2 hs0 = ((const float2*)(src + (size_t)j0 * ED))[lane];
    const float2 hs1 = ((const float2*)(src + (size_t)j1 * ED))[lane];

    float ea0[8], ea1[8];  // row kg handles k = i*4 + kg
    #pragma unroll
    for (int i = 0; i < 8; ++i) {
        const int k  = i * 4 + kg;
        const int jk0 = __shfl(idxreg, k, 64);
        const int jk1 = __shfl(idxreg, 32 + k, 64);
        const uint2 pv0 = ((const uint2*)(PnB + ((size_t)m * NN + jk0) * DD))[dq];
        const uint2 pv1 = ((const uint2*)(PnB + ((size_t)m * NN + jk1) * DD))[dq];
        float p0 = ftanh(S40.x + bflo(pv0.x)) * X4.x;
        float p1 = ftanh(S41.x + bflo(pv1.x)) * X4.x;
        p0 = fmaf(ftanh(S40.y + bfhi(pv0.x)), X4.y, p0);
        p1 = fmaf(ftanh(S41.y + bfhi(pv1.x)), X4.y, p1);
        p0 = fmaf(ftanh(S40.z + bflo(pv0.y)), X4.z, p0);
        p1 = fmaf(ftanh(S41.z + bflo(pv1.y)), X4.z, p1);
        p0 = fmaf(ftanh(S40.w + bfhi(pv0.y)), X4.w, p0);
        p1 = fmaf(ftanh(S41.w + bfhi(pv1.y)), X4.w, p1);
        p0 += __shfl_xor(p0, 1, 64);  p1 += __shfl_xor(p1, 1, 64);
        p0 += __shfl_xor(p0, 2, 64);  p1 += __shfl_xor(p1, 2, 64);
        p0 += __shfl_xor(p0, 4, 64);  p1 += __shfl_xor(p1, 4, 64);
        p0 += __shfl_xor(p0, 8, 64);  p1 += __shfl_xor(p1, 8, 64);
        ea0[i] = p0;
        ea1[i] = p1;
    }

    // softmax x2 with the reference's full-axis baseline (independent)
    const float baseline = (m == 0) ? -1e-9f : (1.0f / (float)NN);
    float mx0 = ea0[0], mx1 = ea1[0];
    #pragma unroll
    for (int i = 1; i < 8; ++i) { mx0 = fmaxf(mx0, ea0[i]); mx1 = fmaxf(mx1, ea1[i]); }
    mx0 = fmaxf(mx0, __shfl_xor(mx0, 16, 64));
    mx1 = fmaxf(mx1, __shfl_xor(mx1, 16, 64));
    mx0 = fmaxf(mx0, __shfl_xor(mx0, 32, 64));
    mx1 = fmaxf(mx1, __shfl_xor(mx1, 32, 64));
    mx0 = fmaxf(mx0, baseline);
    mx1 = fmaxf(mx1, baseline);
    float sum0 = 0.0f, sum1 = 0.0f;
    #pragma unroll
    for (int i = 0; i < 8; ++i) {
        ea0[i] = __expf(ea0[i] - mx0); sum0 += ea0[i];
        ea1[i] = __expf(ea1[i] - mx1); sum1 += ea1[i];
    }
    sum0 += __shfl_xor(sum0, 16, 64);  sum1 += __shfl_xor(sum1, 16, 64);
    sum0 += __shfl_xor(sum0, 32, 64);  sum1 += __shfl_xor(sum1, 32, 64);
    const float inv0 =
        __builtin_amdgcn_rcpf(sum0 + (float)(NN - KK) * __expf(baseline - mx0));
    const float inv1 =
        __builtin_amdgcn_rcpf(sum1 + (float)(NN - KK) * __expf(baseline - mx1));
    #pragma unroll
    for (int i = 0; i < 8; ++i) { ea0[i] *= inv0; ea1[i] *= inv1; }

    // H aggregation: lane covers elements {2*lane, 2*lane+1} of each node
    float2 ha = hs0, hb = hs1;
    #pragma unroll
    for (int k = 0; k < KK; ++k) {
        const float a0 = readlane_f(ea0[k >> 2], (k & 3) * 16);
        const float a1 = readlane_f(ea1[k >> 2], (k & 3) * 16);
        const int  jk0 = __builtin_amdgcn_readlane(idxreg, k);
        const int  jk1 = __builtin_amdgcn_readlane(idxreg, 32 + k);
        const unsigned int o0 = ((const unsigned int*)(otherB + (size_t)jk0 * ED))[lane];
        const unsigned int o1 = ((const unsigned int*)(otherB + (size_t)jk1 * ED))[lane];
        ha.x = fmaf(a0, bflo(o0), ha.x);
        hb.x = fmaf(a1, bflo(o1), hb.x);
        ha.y = fmaf(a0, bfhi(o0), ha.y);
        hb.y = fmaf(a1, bfhi(o1), hb.y);
    }
    const unsigned int hu0 =
        (unsigned int)f2bf(ha.x) | ((unsigned int)f2bf(ha.y) << 16);
    const unsigned int hu1 =
        (unsigned int)f2bf(hb.x) | ((unsigned int)f2bf(hb.y) << 16);
    ((unsigned int*)(HoutB + ((size_t)m * NN + j0) * ED))[lane] = hu0;
    ((unsigned int*)(HoutB + ((size_t)m * NN + j1) * ED))[lane] = hu1;
}

// -------------------------------------------------------------------------
// sem_mfma: per-block beta partials, direct slot write (no atomics).
// grid: (NN/64, MM), block 256.
// -------------------------------------------------------------------------
__global__ __launch_bounds__(256) void sem_mfma(
    const unsigned short* __restrict__ HB,    // [MM,NN,ED] bf16
    const unsigned short* __restrict__ WqT,   // [MM,DD,ED] bf16
    const float* __restrict__ Bq,             // [MM,DD]
    const float* __restrict__ Qv,             // [MM,DD]
    float* __restrict__ bp)                   // [MM*128]
{
    const int m    = blockIdx.y;
    const int tid  = threadIdx.x;
    const int wave = tid >> 6;
    const int lane = tid & 63;
    const int nrow = lane & 15;
    const int quad = lane >> 4;
    const int r0   = blockIdx.x * 64 + wave * 16;

    __shared__ float red_sh[4];

    const short8* A8 = (const short8*)(HB + ((size_t)m * NN + r0 + nrow) * ED);
    const short8* B8 = (const short8*)(WqT + (size_t)m * DD * ED);

    f32x4 acc0 = {0.f, 0.f, 0.f, 0.f};
    f32x4 acc1 = {0.f, 0.f, 0.f, 0.f};
    f32x4 acc2 = {0.f, 0.f, 0.f, 0.f};
    f32x4 acc3 = {0.f, 0.f, 0.f, 0.f};

    #pragma unroll
    for (int kq = 0; kq < 4; ++kq) {
        const short8 a = A8[kq * 4 + quad];
        const short8 b0 = B8[(0 * 16 + nrow) * 16 + kq * 4 + quad];
        const short8 b1 = B8[(1 * 16 + nrow) * 16 + kq * 4 + quad];
        const short8 b2 = B8[(2 * 16 + nrow) * 16 + kq * 4 + quad];
        const short8 b3 = B8[(3 * 16 + nrow) * 16 + kq * 4 + quad];
        acc0 = __builtin_amdgcn_mfma_f32_16x16x32_bf16(a, b0, acc0, 0, 0, 0);
        acc1 = __builtin_amdgcn_mfma_f32_16x16x32_bf16(a, b1, acc1, 0, 0, 0);
        acc2 = __builtin_amdgcn_mfma_f32_16x16x32_bf16(a, b2, acc2, 0, 0, 0);
        acc3 = __builtin_amdgcn_mfma_f32_16x16x32_bf16(a, b3, acc3, 0, 0, 0);
    }

    f32x4 accs[4] = {acc0, acc1, acc2, acc3};
    float part = 0.0f;
    #pragma unroll
    for (int t = 0; t < 4; ++t) {
        const int d = t * 16 + nrow;
        const float bq = Bq[m * DD + d];
        const float qv = Qv[m * DD + d];
        #pragma unroll
        for (int reg = 0; reg < 4; ++reg)
            part = fmaf(ftanh(accs[t][reg] + bq), qv, part);
    }
    #pragma unroll
    for (int off = 32; off; off >>= 1) part += __shfl_xor(part, off, 64);
    if (lane == 0) red_sh[wave] = part;
    __syncthreads();
    if (tid == 0)
        bp[m * 128 + blockIdx.x] =
            (red_sh[0] + red_sh[1]) + (red_sh[2] + red_sh[3]);
}

// -------------------------------------------------------------------------
// combine: computes beta softmax from bp in-kernel (wave 0, redundant per
// block — 2KB L2 reads, removes the beta_reduce launch), then
// out = sum_m bw[m]*H[m]. Kernel-boundary acquire makes bp visible.
// grid: (NN*ED/4/256), block 256.
// -------------------------------------------------------------------------
__global__ __launch_bounds__(256) void combine_kernel(
    const unsigned short* __restrict__ HB,  // [MM,NN,ED] bf16
    const float* __restrict__ bp,           // [MM*128] partials
    float* __restrict__ outp,               // [NN,ED] f32
    unsigned short* __restrict__ outB)      // [NN,ED] bf16 or nullptr
{
    __shared__ float bw_sh[4];
    const int tid = threadIdx.x;
    if (tid < 64) {
        const int m = tid >> 4, t = tid & 15;
        float s = 0.0f;
        #pragma unroll
        for (int i = 0; i < 8; ++i)
            s += bp[m * 128 + t + i * 16];
        s += __shfl_xor(s, 1, 64);
        s += __shfl_xor(s, 2, 64);
        s += __shfl_xor(s, 4, 64);
        s += __shfl_xor(s, 8, 64);
        const float v = s * (1.0f / (float)NN);
        float mx = v;
        mx = fmaxf(mx, __shfl_xor(mx, 16, 64));
        mx = fmaxf(mx, __shfl_xor(mx, 32, 64));
        const float e = expf(v - mx);
        float es = e;
        es += __shfl_xor(es, 16, 64);
        es += __shfl_xor(es, 32, 64);
        if (t == 0) bw_sh[m] = e / es;
    }
    __syncthreads();

    const int i = blockIdx.x * 256 + tid;           // uint2 (4-elem) index
    const size_t st = (size_t)NN * ED / 4;
    const uint2* h = (const uint2*)HB;
    float r0 = 0.f, r1 = 0.f, r2 = 0.f, r3 = 0.f;
    #pragma unroll
    for (int s = 0; s < MM; ++s) {
        const float b = bw_sh[s];
        const uint2 v = h[s * st + i];
        r0 = fmaf(b, bflo(v.x), r0);
        r1 = fmaf(b, bfhi(v.x), r1);
        r2 = fmaf(b, bflo(v.y), r2);
        r3 = fmaf(b, bfhi(v.y), r3);
    }
    float4 o; o.x = r0; o.y = r1; o.z = r2; o.w = r3;
    ((float4*)outp)[i] = o;
    if (outB) {
        uint2 ob;
        ob.x = (unsigned int)f2bf(r0) | ((unsigned int)f2bf(r1) << 16);
        ob.y = (unsigned int)f2bf(r2) | ((unsigned int)f2bf(r3) << 16);
        ((uint2*)outB)[i] = ob;
    }
}

// -------------------------------------------------------------------------
extern "C" void kernel_launch(void* const* d_in, const int* in_sizes, int n_in,
                              void* d_out, int out_size, void* d_ws, size_t ws_size,
                              hipStream_t stream)
{
    // dict order: user, product, V, X, W_p, B_p, W_q, B_q, Q, user_nbrs, product_nbrs
    const float* user    = (const float*)d_in[0];
    const float* product = (const float*)d_in[1];
    const float* V   = (const float*)d_in[2];
    const float* X   = (const float*)d_in[3];
    const float* W_p = (const float*)d_in[4];
    const float* B_p = (const float*)d_in[5];
    const float* W_q = (const float*)d_in[6];
    const float* B_q = (const float*)d_in[7];
    const float* Q   = (const float*)d_in[8];
    const int* user_nbrs    = (const int*)d_in[9];
    const int* product_nbrs = (const int*)d_in[10];

    float* out  = (float*)d_out;            // [2,NN,ED] f32
    float* out0 = out;
    float* out1 = out + (size_t)NN * ED;

    // workspace layout
    float* ws = (float*)d_ws;
    float* bp = ws;                               // 512 (pad 1024)
    float* S  = bp + 1024;                        // MM*NN*DD f32
    unsigned short* us = (unsigned short*)(S + (size_t)MM * NN * DD);
    unsigned short* PnB      = us;                             // MM*NN*DD
    unsigned short* HB       = PnB + (size_t)MM * NN * DD;     // MM*NN*ED
    unsigned short* userB    = HB + (size_t)MM * NN * ED;      // NN*ED
    unsigned short* productB = userB + (size_t)NN * ED;        // NN*ED
    unsigned short* oB       = productB + (size_t)NN * ED;     // NN*ED
    unsigned short* VT       = oB + (size_t)NN * ED;           // 2*MM*DD*ED
    unsigned short* PT       = VT + (size_t)2 * MM * DD * ED;
    unsigned short* QT       = PT + (size_t)2 * MM * DD * ED;

    const size_t MED = (size_t)MM * ED * DD;   // per-phase weight slice
    const size_t MD  = (size_t)MM * DD;

    const dim3 gM2(NN / 64, MM, 2);            // fused proj grid
    const dim3 gM(NN / 64, MM);                // sem grid
    const dim3 gA(NN / 8, MM);                 // attn grid (2 nodes/wave)
    const int cBlocks = (NN * ED / 4) / 256;   // 1024

    // ---------------- prep: conversions + transposes, one launch ----------
    prep_kernel<<<dim3(1024, 5), 256, 0, stream>>>(user, userB, product, productB,
                                                   V, VT, W_p, PT, W_q, QT);

    // ===================== phase 0: user side =====================
    {
        proj2_mfma<<<gM2, 256, 0, stream>>>(userB, VT, B_p, S,
                                            productB, PT, PnB);
        attn_kernel<<<gA, 256, 0, stream>>>(user, productB, user_nbrs,
                                            S, PnB, X, HB);
        sem_mfma<<<gM, 256, 0, stream>>>(HB, QT, B_q, Q, bp);
        combine_kernel<<<cBlocks, 256, 0, stream>>>(HB, bp, out0, oB);
    }

    // ===================== phase 1: product side ==================
    // attends over the UPDATED user embeddings (= out0 / oB)
    {
        proj2_mfma<<<gM2, 256, 0, stream>>>(productB, VT + MED, B_p + MD, S,
                                            oB, PT + MED, PnB);
        attn_kernel<<<gA, 256, 0, stream>>>(product, oB, product_nbrs,
                                            S, PnB, X + MD, HB);
        sem_mfma<<<gM, 256, 0, stream>>>(HB, QT + MED, B_q + MD, Q + MD, bp);
        combine_kernel<<<cBlocks, 256, 0, stream>>>(HB, bp, out1, nullptr);
    }
}

// Round 14
// 203.707 us; speedup vs baseline: 1.0421x; 1.0273x over previous
//
#include <hip/hip_runtime.h>
#include <hip/hip_bf16.h>

// Problem constants (fixed by the reference)
#define NN 8192   // nodes per side
#define ED 128    // embedding dim E
#define DD 64     // attention dim D
#define KK 32     // neighbors per node
#define MM 4      // metapaths

typedef __attribute__((ext_vector_type(8))) short short8;   // 8 bf16 (4 VGPRs)
typedef __attribute__((ext_vector_type(4))) float f32x4;    // MFMA acc

// raw v_exp_f32 (2^x); fallback multiplies back to e-base expf
#if __has_builtin(__builtin_amdgcn_exp2f)
#define EXP2R(x) __builtin_amdgcn_exp2f(x)
#else
#define EXP2R(x) __expf((x) * 0.6931471805599453f)
#endif
#define C2LOG2E 2.8853900817779268f   // 2*log2(e)

// tanh from pre-scaled arg v = x*2*log2(e): 1 - 2*rcp(2^v + 1)
__device__ __forceinline__ float ftanh_pre(float v)
{
    return fmaf(-2.0f, __builtin_amdgcn_rcpf(EXP2R(v) + 1.0f), 1.0f);
}
// plain fast tanh (sem epilogue)
__device__ __forceinline__ float ftanh(float x)
{
    return ftanh_pre(x * C2LOG2E);
}

__device__ __forceinline__ unsigned short f2bf(float x)
{
    __hip_bfloat16 b = __float2bfloat16(x);
    return *reinterpret_cast<unsigned short*>(&b);
}
__device__ __forceinline__ float bflo(unsigned int u) { return __uint_as_float(u << 16); }
__device__ __forceinline__ float bfhi(unsigned int u) { return __uint_as_float(u & 0xFFFF0000u); }
__device__ __forceinline__ float readlane_f(float v, int lane)
{
    return __uint_as_float(__builtin_amdgcn_readlane(__float_as_uint(v), lane));
}

// -------------------------------------------------------------------------
// prep_kernel: one launch for all input reformatting.
//  y=0: user f32->bf16   y=1: product f32->bf16   (x < 1024, 4 elems/thr)
//  y=2/3/4: V/W_p/W_q f32 [S,ED,DD] -> bf16 [S,DD,ED]  (x < 256)
// -------------------------------------------------------------------------
__global__ __launch_bounds__(256) void prep_kernel(
    const float* __restrict__ user, unsigned short* __restrict__ userB,
    const float* __restrict__ product, unsigned short* __restrict__ productB,
    const float* __restrict__ V, unsigned short* __restrict__ VT,
    const float* __restrict__ Wp, unsigned short* __restrict__ PT,
    const float* __restrict__ Wq, unsigned short* __restrict__ QT)
{
    const int y = blockIdx.y;
    if (y < 2) {
        const float* in = y ? product : user;
        unsigned short* out = y ? productB : userB;
        const int i = blockIdx.x * 256 + threadIdx.x;
        const float4 v = ((const float4*)in)[i];
        uint2 o;
        o.x = (unsigned int)f2bf(v.x) | ((unsigned int)f2bf(v.y) << 16);
        o.y = (unsigned int)f2bf(v.z) | ((unsigned int)f2bf(v.w) << 16);
        ((uint2*)out)[i] = o;
    } else {
        if (blockIdx.x >= 256) return;
        const float* in = (y == 2) ? V : (y == 3) ? Wp : Wq;
        unsigned short* out = (y == 2) ? VT : (y == 3) ? PT : QT;
        const int gid = blockIdx.x * 256 + threadIdx.x;
        const int s   = gid >> 13;          // ED*DD = 8192
        const int rem = gid & 8191;
        const int e   = rem >> 6;
        const int d   = rem & 63;
        out[((size_t)s * DD + d) * ED + e] = f2bf(in[gid]);
    }
}

// -------------------------------------------------------------------------
// proj2_mfma: both per-phase projections in one launch (blockIdx.z):
//   z=0: S  = emb0 @ Wt0 + Bias0 -> f32 outF0
//   z=1: Pn = emb1 @ Wt1         -> bf16 outB1
// grid: (NN/64, MM, 2).
// -------------------------------------------------------------------------
__global__ __launch_bounds__(256) void proj2_mfma(
    const unsigned short* __restrict__ emb0,  // [NN,ED] bf16
    const unsigned short* __restrict__ Wt0,   // [MM,DD,ED] bf16
    const float* __restrict__ Bias0,          // [MM,DD]
    float* __restrict__ outF0,                // [MM,NN,DD] f32
    const unsigned short* __restrict__ emb1,  // [NN,ED] bf16
    const unsigned short* __restrict__ Wt1,   // [MM,DD,ED] bf16
    unsigned short* __restrict__ outB1)       // [MM,NN,DD] bf16
{
    const int z    = blockIdx.z;
    const int m    = blockIdx.y;
    const int tid  = threadIdx.x;
    const int wave = tid >> 6;
    const int lane = tid & 63;
    const int nrow = lane & 15;
    const int quad = lane >> 4;
    const int r0   = blockIdx.x * 64 + wave * 16;

    const unsigned short* embB = z ? emb1 : emb0;
    const unsigned short* WtB  = z ? Wt1 : Wt0;

    const short8* A8 = (const short8*)(embB + (size_t)(r0 + nrow) * ED);
    const short8* B8 = (const short8*)(WtB + (size_t)m * DD * ED);

    f32x4 acc0 = {0.f, 0.f, 0.f, 0.f};
    f32x4 acc1 = {0.f, 0.f, 0.f, 0.f};
    f32x4 acc2 = {0.f, 0.f, 0.f, 0.f};
    f32x4 acc3 = {0.f, 0.f, 0.f, 0.f};

    #pragma unroll
    for (int kq = 0; kq < 4; ++kq) {
        const short8 a = A8[kq * 4 + quad];
        const short8 b0 = B8[(0 * 16 + nrow) * 16 + kq * 4 + quad];
        const short8 b1 = B8[(1 * 16 + nrow) * 16 + kq * 4 + quad];
        const short8 b2 = B8[(2 * 16 + nrow) * 16 + kq * 4 + quad];
        const short8 b3 = B8[(3 * 16 + nrow) * 16 + kq * 4 + quad];
        acc0 = __builtin_amdgcn_mfma_f32_16x16x32_bf16(a, b0, acc0, 0, 0, 0);
        acc1 = __builtin_amdgcn_mfma_f32_16x16x32_bf16(a, b1, acc1, 0, 0, 0);
        acc2 = __builtin_amdgcn_mfma_f32_16x16x32_bf16(a, b2, acc2, 0, 0, 0);
        acc3 = __builtin_amdgcn_mfma_f32_16x16x32_bf16(a, b3, acc3, 0, 0, 0);
    }

    f32x4 accs[4] = {acc0, acc1, acc2, acc3};
    if (z == 0) {
        #pragma unroll
        for (int t = 0; t < 4; ++t) {
            const int d = t * 16 + nrow;
            const float bv = Bias0[m * DD + d];
            #pragma unroll
            for (int reg = 0; reg < 4; ++reg) {
                const int r = r0 + quad * 4 + reg;
                outF0[((size_t)m * NN + r) * DD + d] = accs[t][reg] + bv;
            }
        }
    } else {
        #pragma unroll
        for (int t = 0; t < 4; ++t) {
            const int d = t * 16 + nrow;
            #pragma unroll
            for (int reg = 0; reg < 4; ++reg) {
                const int r = r0 + quad * 4 + reg;
                outB1[((size_t)m * NN + r) * DD + d] = f2bf(accs[t][reg]);
            }
        }
    }
}

// -------------------------------------------------------------------------
// attn_kernel v5: 2 nodes/wave; lane = (k-row = lane>>3, d-octet = lane&7).
// Per score iter: ONE uint4 (16B) Pn load per node (8 bf16 d-vals), 8
// tanh-components via fma-folded exp2 (1 fewer full-rate op each), 3-step
// butterfly (xor 1/2/4). 4 iters cover 32 k. grid: (NN/8, MM), block 256.
// -------------------------------------------------------------------------
__global__ __launch_bounds__(256) void attn_kernel(
    const float* __restrict__ src,             // [NN,ED] f32
    const unsigned short* __restrict__ otherB, // [NN,ED] bf16
    const int*   __restrict__ nbrs,            // [MM,NN,KK]
    const float* __restrict__ S,               // [MM,NN,DD] f32
    const unsigned short* __restrict__ PnB,    // [MM,NN,DD] bf16
    const float* __restrict__ Xv,              // [MM,DD] f32
    unsigned short* __restrict__ HoutB)        // [MM,NN,ED] bf16
{
    const int m    = blockIdx.y;
    const int tid  = threadIdx.x;
    const int w    = tid >> 6;
    const int lane = tid & 63;
    const int g    = blockIdx.x * 4 + w;   // wave id
    const int j0   = g * 2;
    const int j1   = g * 2 + 1;

    const int kr = lane >> 3;        // k-row (0..7)
    const int d8 = lane & 7;         // d-octet: d = d8*8 .. d8*8+7

    // neighbor ids: lanes 0-31 -> j0's k, lanes 32-63 -> j1's k
    const int jj = (lane < 32) ? j0 : j1;
    const int idxreg = nbrs[((size_t)m * NN + jj) * KK + (lane & 31)];

    // S rows pre-scaled by 2*log2(e); X row plain. 8 components per lane.
    float S0c[8], S1c[8], X8[8];
    {
        const float4 a0 = *(const float4*)(S + ((size_t)m * NN + j0) * DD + d8 * 8);
        const float4 a1 = *(const float4*)(S + ((size_t)m * NN + j0) * DD + d8 * 8 + 4);
        const float4 b0 = *(const float4*)(S + ((size_t)m * NN + j1) * DD + d8 * 8);
        const float4 b1 = *(const float4*)(S + ((size_t)m * NN + j1) * DD + d8 * 8 + 4);
        const float4 x0 = *(const float4*)(Xv + (size_t)m * DD + d8 * 8);
        const float4 x1 = *(const float4*)(Xv + (size_t)m * DD + d8 * 8 + 4);
        S0c[0]=a0.x*C2LOG2E; S0c[1]=a0.y*C2LOG2E; S0c[2]=a0.z*C2LOG2E; S0c[3]=a0.w*C2LOG2E;
        S0c[4]=a1.x*C2LOG2E; S0c[5]=a1.y*C2LOG2E; S0c[6]=a1.z*C2LOG2E; S0c[7]=a1.w*C2LOG2E;
        S1c[0]=b0.x*C2LOG2E; S1c[1]=b0.y*C2LOG2E; S1c[2]=b0.z*C2LOG2E; S1c[3]=b0.w*C2LOG2E;
        S1c[4]=b1.x*C2LOG2E; S1c[5]=b1.y*C2LOG2E; S1c[6]=b1.z*C2LOG2E; S1c[7]=b1.w*C2LOG2E;
        X8[0]=x0.x; X8[1]=x0.y; X8[2]=x0.z; X8[3]=x0.w;
        X8[4]=x1.x; X8[5]=x1.y; X8[6]=x1.z; X8[7]=x1.w;
    }
    const float2 hs0 = ((const float2*)(src + (size_t)j0 * ED))[lane];
    const float2 hs1 = ((const float2*)(src + (size_t)j1 * ED))[lane];

    float ea0[4], ea1[4];  // row kr handles k = i*8 + kr
    #pragma unroll
    for (int i = 0; i < 4; ++i) {
        const int k   = i * 8 + kr;
        const int jk0 = __shfl(idxreg, k, 64);
        const int jk1 = __shfl(idxreg, 32 + k, 64);
        const uint4 p0 = ((const uint4*)(PnB + ((size_t)m * NN + jk0) * DD))[d8];
        const uint4 p1 = ((const uint4*)(PnB + ((size_t)m * NN + jk1) * DD))[d8];
        const unsigned int pw0[4] = {p0.x, p0.y, p0.z, p0.w};
        const unsigned int pw1[4] = {p1.x, p1.y, p1.z, p1.w};
        float q0 = 0.0f, q1 = 0.0f;
        #pragma unroll
        for (int c = 0; c < 4; ++c) {
            const float lo0 = bflo(pw0[c]), hi0 = bfhi(pw0[c]);
            const float lo1 = bflo(pw1[c]), hi1 = bfhi(pw1[c]);
            q0 = fmaf(ftanh_pre(fmaf(lo0, C2LOG2E, S0c[c*2  ])), X8[c*2  ], q0);
            q1 = fmaf(ftanh_pre(fmaf(lo1, C2LOG2E, S1c[c*2  ])), X8[c*2  ], q1);
            q0 = fmaf(ftanh_pre(fmaf(hi0, C2LOG2E, S0c[c*2+1])), X8[c*2+1], q0);
            q1 = fmaf(ftanh_pre(fmaf(hi1, C2LOG2E, S1c[c*2+1])), X8[c*2+1], q1);
        }
        q0 += __shfl_xor(q0, 1, 64);  q1 += __shfl_xor(q1, 1, 64);
        q0 += __shfl_xor(q0, 2, 64);  q1 += __shfl_xor(q1, 2, 64);
        q0 += __shfl_xor(q0, 4, 64);  q1 += __shfl_xor(q1, 4, 64);
        ea0[i] = q0;
        ea1[i] = q1;
    }

    // softmax x2 with the reference's full-axis baseline
    const float baseline = (m == 0) ? -1e-9f : (1.0f / (float)NN);
    float mx0 = ea0[0], mx1 = ea1[0];
    #pragma unroll
    for (int i = 1; i < 4; ++i) { mx0 = fmaxf(mx0, ea0[i]); mx1 = fmaxf(mx1, ea1[i]); }
    mx0 = fmaxf(mx0, __shfl_xor(mx0, 8, 64));
    mx1 = fmaxf(mx1, __shfl_xor(mx1, 8, 64));
    mx0 = fmaxf(mx0, __shfl_xor(mx0, 16, 64));
    mx1 = fmaxf(mx1, __shfl_xor(mx1, 16, 64));
    mx0 = fmaxf(mx0, __shfl_xor(mx0, 32, 64));
    mx1 = fmaxf(mx1, __shfl_xor(mx1, 32, 64));
    mx0 = fmaxf(mx0, baseline);
    mx1 = fmaxf(mx1, baseline);
    float sum0 = 0.0f, sum1 = 0.0f;
    #pragma unroll
    for (int i = 0; i < 4; ++i) {
        ea0[i] = __expf(ea0[i] - mx0); sum0 += ea0[i];
        ea1[i] = __expf(ea1[i] - mx1); sum1 += ea1[i];
    }
    sum0 += __shfl_xor(sum0, 8, 64);   sum1 += __shfl_xor(sum1, 8, 64);
    sum0 += __shfl_xor(sum0, 16, 64);  sum1 += __shfl_xor(sum1, 16, 64);
    sum0 += __shfl_xor(sum0, 32, 64);  sum1 += __shfl_xor(sum1, 32, 64);
    const float inv0 =
        __builtin_amdgcn_rcpf(sum0 + (float)(NN - KK) * __expf(baseline - mx0));
    const float inv1 =
        __builtin_amdgcn_rcpf(sum1 + (float)(NN - KK) * __expf(baseline - mx1));
    #pragma unroll
    for (int i = 0; i < 4; ++i) { ea0[i] *= inv0; ea1[i] *= inv1; }

    // H aggregation: lane covers elements {2*lane, 2*lane+1} of each node.
    // A for k lives in e-index k>>3 of row k&7 -> readlane (k&7)*8.
    float2 ha = hs0, hb = hs1;
    #pragma unroll
    for (int k = 0; k < KK; ++k) {
        const float a0 = readlane_f(ea0[k >> 3], (k & 7) * 8);
        const float a1 = readlane_f(ea1[k >> 3], (k & 7) * 8);
        const int  jk0 = __builtin_amdgcn_readlane(idxreg, k);
        const int  jk1 = __builtin_amdgcn_readlane(idxreg, 32 + k);
        const unsigned int o0 = ((const unsigned int*)(otherB + (size_t)jk0 * ED))[lane];
        const unsigned int o1 = ((const unsigned int*)(otherB + (size_t)jk1 * ED))[lane];
        ha.x = fmaf(a0, bflo(o0), ha.x);
        hb.x = fmaf(a1, bflo(o1), hb.x);
        ha.y = fmaf(a0, bfhi(o0), ha.y);
        hb.y = fmaf(a1, bfhi(o1), hb.y);
    }
    const unsigned int hu0 =
        (unsigned int)f2bf(ha.x) | ((unsigned int)f2bf(ha.y) << 16);
    const unsigned int hu1 =
        (unsigned int)f2bf(hb.x) | ((unsigned int)f2bf(hb.y) << 16);
    ((unsigned int*)(HoutB + ((size_t)m * NN + j0) * ED))[lane] = hu0;
    ((unsigned int*)(HoutB + ((size_t)m * NN + j1) * ED))[lane] = hu1;
}

// -------------------------------------------------------------------------
// sem_mfma: per-block beta partials, direct slot write (no atomics).
// grid: (NN/64, MM), block 256.
// -------------------------------------------------------------------------
__global__ __launch_bounds__(256) void sem_mfma(
    const unsigned short* __restrict__ HB,    // [MM,NN,ED] bf16
    const unsigned short* __restrict__ WqT,   // [MM,DD,ED] bf16
    const float* __restrict__ Bq,             // [MM,DD]
    const float* __restrict__ Qv,             // [MM,DD]
    float* __restrict__ bp)                   // [MM*128]
{
    const int m    = blockIdx.y;
    const int tid  = threadIdx.x;
    const int wave = tid >> 6;
    const int lane = tid & 63;
    const int nrow = lane & 15;
    const int quad = lane >> 4;
    const int r0   = blockIdx.x * 64 + wave * 16;

    __shared__ float red_sh[4];

    const short8* A8 = (const short8*)(HB + ((size_t)m * NN + r0 + nrow) * ED);
    const short8* B8 = (const short8*)(WqT + (size_t)m * DD * ED);

    f32x4 acc0 = {0.f, 0.f, 0.f, 0.f};
    f32x4 acc1 = {0.f, 0.f, 0.f, 0.f};
    f32x4 acc2 = {0.f, 0.f, 0.f, 0.f};
    f32x4 acc3 = {0.f, 0.f, 0.f, 0.f};

    #pragma unroll
    for (int kq = 0; kq < 4; ++kq) {
        const short8 a = A8[kq * 4 + quad];
        const short8 b0 = B8[(0 * 16 + nrow) * 16 + kq * 4 + quad];
        const short8 b1 = B8[(1 * 16 + nrow) * 16 + kq * 4 + quad];
        const short8 b2 = B8[(2 * 16 + nrow) * 16 + kq * 4 + quad];
        const short8 b3 = B8[(3 * 16 + nrow) * 16 + kq * 4 + quad];
        acc0 = __builtin_amdgcn_mfma_f32_16x16x32_bf16(a, b0, acc0, 0, 0, 0);
        acc1 = __builtin_amdgcn_mfma_f32_16x16x32_bf16(a, b1, acc1, 0, 0, 0);
        acc2 = __builtin_amdgcn_mfma_f32_16x16x32_bf16(a, b2, acc2, 0, 0, 0);
        acc3 = __builtin_amdgcn_mfma_f32_16x16x32_bf16(a, b3, acc3, 0, 0, 0);
    }

    f32x4 accs[4] = {acc0, acc1, acc2, acc3};
    float part = 0.0f;
    #pragma unroll
    for (int t = 0; t < 4; ++t) {
        const int d = t * 16 + nrow;
        const float bq = Bq[m * DD + d];
        const float qv = Qv[m * DD + d];
        #pragma unroll
        for (int reg = 0; reg < 4; ++reg)
            part = fmaf(ftanh(accs[t][reg] + bq), qv, part);
    }
    #pragma unroll
    for (int off = 32; off; off >>= 1) part += __shfl_xor(part, off, 64);
    if (lane == 0) red_sh[wave] = part;
    __syncthreads();
    if (tid == 0)
        bp[m * 128 + blockIdx.x] =
            (red_sh[0] + red_sh[1]) + (red_sh[2] + red_sh[3]);
}

// -------------------------------------------------------------------------
// combine: beta softmax from bp in-kernel (wave 0, redundant per block),
// then out = sum_m bw[m]*H[m]. grid: (NN*ED/4/256), block 256.
// -------------------------------------------------------------------------
__global__ __launch_bounds__(256) void combine_kernel(
    const unsigned short* __restrict__ HB,  // [MM,NN,ED] bf16
    const float* __restrict__ bp,           // [MM*128] partials
    float* __restrict__ outp,               // [NN,ED] f32
    unsigned short* __restrict__ outB)      // [NN,ED] bf16 or nullptr
{
    __shared__ float bw_sh[4];
    const int tid = threadIdx.x;
    if (tid < 64) {
        const int m = tid >> 4, t = tid & 15;
        float s = 0.0f;
        #pragma unroll
        for (int i = 0; i < 8; ++i)
            s += bp[m * 128 + t + i * 16];
        s += __shfl_xor(s, 1, 64);
        s += __shfl_xor(s, 2, 64);
        s += __shfl_xor(s, 4, 64);
        s += __shfl_xor(s, 8, 64);
        const float v = s * (1.0f / (float)NN);
        float mx = v;
        mx = fmaxf(mx, __shfl_xor(mx, 16, 64));
        mx = fmaxf(mx, __shfl_xor(mx, 32, 64));
        const float e = expf(v - mx);
        float es = e;
        es += __shfl_xor(es, 16, 64);
        es += __shfl_xor(es, 32, 64);
        if (t == 0) bw_sh[m] = e / es;
    }
    __syncthreads();

    const int i = blockIdx.x * 256 + tid;           // uint2 (4-elem) index
    const size_t st = (size_t)NN * ED / 4;
    const uint2* h = (const uint2*)HB;
    float r0 = 0.f, r1 = 0.f, r2 = 0.f, r3 = 0.f;
    #pragma unroll
    for (int s = 0; s < MM; ++s) {
        const float b = bw_sh[s];
        const uint2 v = h[s * st + i];
        r0 = fmaf(b, bflo(v.x), r0);
        r1 = fmaf(b, bfhi(v.x), r1);
        r2 = fmaf(b, bflo(v.y), r2);
        r3 = fmaf(b, bfhi(v.y), r3);
    }
    float4 o; o.x = r0; o.y = r1; o.z = r2; o.w = r3;
    ((float4*)outp)[i] = o;
    if (outB) {
        uint2 ob;
        ob.x = (unsigned int)f2bf(r0) | ((unsigned int)f2bf(r1) << 16);
        ob.y = (unsigned int)f2bf(r2) | ((unsigned int)f2bf(r3) << 16);
        ((uint2*)outB)[i] = ob;
    }
}

// -------------------------------------------------------------------------
extern "C" void kernel_launch(void* const* d_in, const int* in_sizes, int n_in,
                              void* d_out, int out_size, void* d_ws, size_t ws_size,
                              hipStream_t stream)
{
    // dict order: user, product, V, X, W_p, B_p, W_q, B_q, Q, user_nbrs, product_nbrs
    const float* user    = (const float*)d_in[0];
    const float* product = (const float*)d_in[1];
    const float* V   = (const float*)d_in[2];
    const float* X   = (const float*)d_in[3];
    const float* W_p = (const float*)d_in[4];
    const float* B_p = (const float*)d_in[5];
    const float* W_q = (const float*)d_in[6];
    const float* B_q = (const float*)d_in[7];
    const float* Q   = (const float*)d_in[8];
    const int* user_nbrs    = (const int*)d_in[9];
    const int* product_nbrs = (const int*)d_in[10];

    float* out  = (float*)d_out;            // [2,NN,ED] f32
    float* out0 = out;
    float* out1 = out + (size_t)NN * ED;

    // workspace layout
    float* ws = (float*)d_ws;
    float* bp = ws;                               // 512 (pad 1024)
    float* S  = bp + 1024;                        // MM*NN*DD f32
    unsigned short* us = (unsigned short*)(S + (size_t)MM * NN * DD);
    unsigned short* PnB      = us;                             // MM*NN*DD
    unsigned short* HB       = PnB + (size_t)MM * NN * DD;     // MM*NN*ED
    unsigned short* userB    = HB + (size_t)MM * NN * ED;      // NN*ED
    unsigned short* productB = userB + (size_t)NN * ED;        // NN*ED
    unsigned short* oB       = productB + (size_t)NN * ED;     // NN*ED
    unsigned short* VT       = oB + (size_t)NN * ED;           // 2*MM*DD*ED
    unsigned short* PT       = VT + (size_t)2 * MM * DD * ED;
    unsigned short* QT       = PT + (size_t)2 * MM * DD * ED;

    const size_t MED = (size_t)MM * ED * DD;   // per-phase weight slice
    const size_t MD  = (size_t)MM * DD;

    const dim3 gM2(NN / 64, MM, 2);            // fused proj grid
    const dim3 gM(NN / 64, MM);                // sem grid
    const dim3 gA(NN / 8, MM);                 // attn grid (2 nodes/wave)
    const int cBlocks = (NN * ED / 4) / 256;   // 1024

    // ---------------- prep: conversions + transposes, one launch ----------
    prep_kernel<<<dim3(1024, 5), 256, 0, stream>>>(user, userB, product, productB,
                                                   V, VT, W_p, PT, W_q, QT);

    // ===================== phase 0: user side =====================
    {
        proj2_mfma<<<gM2, 256, 0, stream>>>(userB, VT, B_p, S,
                                            productB, PT, PnB);
        attn_kernel<<<gA, 256, 0, stream>>>(user, productB, user_nbrs,
                                            S, PnB, X, HB);
        sem_mfma<<<gM, 256, 0, stream>>>(HB, QT, B_q, Q, bp);
        combine_kernel<<<cBlocks, 256, 0, stream>>>(HB, bp, out0, oB);
    }

    // ===================== phase 1: product side ==================
    // attends over the UPDATED user embeddings (= out0 / oB)
    {
        proj2_mfma<<<gM2, 256, 0, stream>>>(productB, VT + MED, B_p + MD, S,
                                            oB, PT + MED, PnB);
        attn_kernel<<<gA, 256, 0, stream>>>(product, oB, product_nbrs,
                                            S, PnB, X + MD, HB);
        sem_mfma<<<gM, 256, 0, stream>>>(HB, QT + MED, B_q + MD, Q + MD, bp);
        combine_kernel<<<cBlocks, 256, 0, stream>>>(HB, bp, out1, nullptr);
    }
}

// Round 15
// 201.549 us; speedup vs baseline: 1.0533x; 1.0107x over previous
//
#include <hip/hip_runtime.h>
#include <hip/hip_bf16.h>

// Problem constants (fixed by the reference)
#define NN 8192   // nodes per side
#define ED 128    // embedding dim E
#define DD 64     // attention dim D
#define KK 32     // neighbors per node
#define MM 4      // metapaths

typedef __attribute__((ext_vector_type(8))) short short8;   // 8 bf16 (4 VGPRs)
typedef __attribute__((ext_vector_type(4))) float f32x4;    // MFMA acc

// raw v_exp_f32 (2^x); fallback multiplies back to e-base expf
#if __has_builtin(__builtin_amdgcn_exp2f)
#define EXP2R(x) __builtin_amdgcn_exp2f(x)
#else
#define EXP2R(x) __expf((x) * 0.6931471805599453f)
#endif
#define C2LOG2E 2.8853900817779268f   // 2*log2(e)

// tanh from pre-scaled arg v = x*2*log2(e): 1 - 2*rcp(2^v + 1)
__device__ __forceinline__ float ftanh_pre(float v)
{
    return fmaf(-2.0f, __builtin_amdgcn_rcpf(EXP2R(v) + 1.0f), 1.0f);
}
// plain fast tanh (sem epilogue)
__device__ __forceinline__ float ftanh(float x)
{
    return ftanh_pre(x * C2LOG2E);
}

__device__ __forceinline__ unsigned short f2bf(float x)
{
    __hip_bfloat16 b = __float2bfloat16(x);
    return *reinterpret_cast<unsigned short*>(&b);
}
__device__ __forceinline__ float bflo(unsigned int u) { return __uint_as_float(u << 16); }
__device__ __forceinline__ float bfhi(unsigned int u) { return __uint_as_float(u & 0xFFFF0000u); }
__device__ __forceinline__ float readlane_f(float v, int lane)
{
    return __uint_as_float(__builtin_amdgcn_readlane(__float_as_uint(v), lane));
}

// -------------------------------------------------------------------------
// prep_kernel: one launch for all input reformatting.
//  y=0: user f32->bf16   y=1: product f32->bf16   (x < 1024, 4 elems/thr)
//  y=2/3/4: V/W_p/W_q f32 [S,ED,DD] -> bf16 [S,DD,ED]  (x < 256)
// -------------------------------------------------------------------------
__global__ __launch_bounds__(256) void prep_kernel(
    const float* __restrict__ user, unsigned short* __restrict__ userB,
    const float* __restrict__ product, unsigned short* __restrict__ productB,
    const float* __restrict__ V, unsigned short* __restrict__ VT,
    const float* __restrict__ Wp, unsigned short* __restrict__ PT,
    const float* __restrict__ Wq, unsigned short* __restrict__ QT)
{
    const int y = blockIdx.y;
    if (y < 2) {
        const float* in = y ? product : user;
        unsigned short* out = y ? productB : userB;
        const int i = blockIdx.x * 256 + threadIdx.x;
        const float4 v = ((const float4*)in)[i];
        uint2 o;
        o.x = (unsigned int)f2bf(v.x) | ((unsigned int)f2bf(v.y) << 16);
        o.y = (unsigned int)f2bf(v.z) | ((unsigned int)f2bf(v.w) << 16);
        ((uint2*)out)[i] = o;
    } else {
        if (blockIdx.x >= 256) return;
        const float* in = (y == 2) ? V : (y == 3) ? Wp : Wq;
        unsigned short* out = (y == 2) ? VT : (y == 3) ? PT : QT;
        const int gid = blockIdx.x * 256 + threadIdx.x;
        const int s   = gid >> 13;          // ED*DD = 8192
        const int rem = gid & 8191;
        const int e   = rem >> 6;
        const int d   = rem & 63;
        out[((size_t)s * DD + d) * ED + e] = f2bf(in[gid]);
    }
}

// -------------------------------------------------------------------------
// proj2_mfma: both per-phase projections in one launch (blockIdx.z):
//   z=0: S  = (emb0 @ Wt0 + Bias0) * 2*log2(e) -> f32 outF0 (PRE-SCALED for
//        attn's exp2-based tanh — S feeds only attn)
//   z=1: Pn = emb1 @ Wt1 -> bf16 outB1
// grid: (NN/64, MM, 2).
// -------------------------------------------------------------------------
__global__ __launch_bounds__(256) void proj2_mfma(
    const unsigned short* __restrict__ emb0,  // [NN,ED] bf16
    const unsigned short* __restrict__ Wt0,   // [MM,DD,ED] bf16
    const float* __restrict__ Bias0,          // [MM,DD]
    float* __restrict__ outF0,                // [MM,NN,DD] f32 (scaled)
    const unsigned short* __restrict__ emb1,  // [NN,ED] bf16
    const unsigned short* __restrict__ Wt1,   // [MM,DD,ED] bf16
    unsigned short* __restrict__ outB1)       // [MM,NN,DD] bf16
{
    const int z    = blockIdx.z;
    const int m    = blockIdx.y;
    const int tid  = threadIdx.x;
    const int wave = tid >> 6;
    const int lane = tid & 63;
    const int nrow = lane & 15;
    const int quad = lane >> 4;
    const int r0   = blockIdx.x * 64 + wave * 16;

    const unsigned short* embB = z ? emb1 : emb0;
    const unsigned short* WtB  = z ? Wt1 : Wt0;

    const short8* A8 = (const short8*)(embB + (size_t)(r0 + nrow) * ED);
    const short8* B8 = (const short8*)(WtB + (size_t)m * DD * ED);

    f32x4 acc0 = {0.f, 0.f, 0.f, 0.f};
    f32x4 acc1 = {0.f, 0.f, 0.f, 0.f};
    f32x4 acc2 = {0.f, 0.f, 0.f, 0.f};
    f32x4 acc3 = {0.f, 0.f, 0.f, 0.f};

    #pragma unroll
    for (int kq = 0; kq < 4; ++kq) {
        const short8 a = A8[kq * 4 + quad];
        const short8 b0 = B8[(0 * 16 + nrow) * 16 + kq * 4 + quad];
        const short8 b1 = B8[(1 * 16 + nrow) * 16 + kq * 4 + quad];
        const short8 b2 = B8[(2 * 16 + nrow) * 16 + kq * 4 + quad];
        const short8 b3 = B8[(3 * 16 + nrow) * 16 + kq * 4 + quad];
        acc0 = __builtin_amdgcn_mfma_f32_16x16x32_bf16(a, b0, acc0, 0, 0, 0);
        acc1 = __builtin_amdgcn_mfma_f32_16x16x32_bf16(a, b1, acc1, 0, 0, 0);
        acc2 = __builtin_amdgcn_mfma_f32_16x16x32_bf16(a, b2, acc2, 0, 0, 0);
        acc3 = __builtin_amdgcn_mfma_f32_16x16x32_bf16(a, b3, acc3, 0, 0, 0);
    }

    f32x4 accs[4] = {acc0, acc1, acc2, acc3};
    if (z == 0) {
        #pragma unroll
        for (int t = 0; t < 4; ++t) {
            const int d = t * 16 + nrow;
            const float bv = Bias0[m * DD + d];
            #pragma unroll
            for (int reg = 0; reg < 4; ++reg) {
                const int r = r0 + quad * 4 + reg;
                outF0[((size_t)m * NN + r) * DD + d] =
                    (accs[t][reg] + bv) * C2LOG2E;
            }
        }
    } else {
        #pragma unroll
        for (int t = 0; t < 4; ++t) {
            const int d = t * 16 + nrow;
            #pragma unroll
            for (int reg = 0; reg < 4; ++reg) {
                const int r = r0 + quad * 4 + reg;
                outB1[((size_t)m * NN + r) * DD + d] = f2bf(accs[t][reg]);
            }
        }
    }
}

// -------------------------------------------------------------------------
// attn_kernel v6: 2 nodes/wave; lane = (k-row = lane>>3, d-octet = lane&7).
// Score contribution folded: X*tanh(x) = X - 2X*rcp(exp2(x*C)+1), with
// per-lane precomputed m2X[c]=-2X[c] and q initialized to sumX — 6 VALU
// ops per tanh-component (was 7). S arrives pre-scaled by C from proj2.
// grid: (NN/8, MM), block 256.
// -------------------------------------------------------------------------
__global__ __launch_bounds__(256) void attn_kernel(
    const float* __restrict__ src,             // [NN,ED] f32
    const unsigned short* __restrict__ otherB, // [NN,ED] bf16
    const int*   __restrict__ nbrs,            // [MM,NN,KK]
    const float* __restrict__ S,               // [MM,NN,DD] f32, pre-scaled
    const unsigned short* __restrict__ PnB,    // [MM,NN,DD] bf16
    const float* __restrict__ Xv,              // [MM,DD] f32
    unsigned short* __restrict__ HoutB)        // [MM,NN,ED] bf16
{
    const int m    = blockIdx.y;
    const int tid  = threadIdx.x;
    const int w    = tid >> 6;
    const int lane = tid & 63;
    const int g    = blockIdx.x * 4 + w;   // wave id
    const int j0   = g * 2;
    const int j1   = g * 2 + 1;

    const int kr = lane >> 3;        // k-row (0..7)
    const int d8 = lane & 7;         // d-octet: d = d8*8 .. d8*8+7

    // neighbor ids: lanes 0-31 -> j0's k, lanes 32-63 -> j1's k
    const int jj = (lane < 32) ? j0 : j1;
    const int idxreg = nbrs[((size_t)m * NN + jj) * KK + (lane & 31)];

    // S rows (already scaled by 2*log2(e) in proj2); X -> m2X = -2X, sumX.
    float S0c[8], S1c[8], m2X[8];
    float sumX;
    {
        const float4 a0 = *(const float4*)(S + ((size_t)m * NN + j0) * DD + d8 * 8);
        const float4 a1 = *(const float4*)(S + ((size_t)m * NN + j0) * DD + d8 * 8 + 4);
        const float4 b0 = *(const float4*)(S + ((size_t)m * NN + j1) * DD + d8 * 8);
        const float4 b1 = *(const float4*)(S + ((size_t)m * NN + j1) * DD + d8 * 8 + 4);
        const float4 x0 = *(const float4*)(Xv + (size_t)m * DD + d8 * 8);
        const float4 x1 = *(const float4*)(Xv + (size_t)m * DD + d8 * 8 + 4);
        S0c[0]=a0.x; S0c[1]=a0.y; S0c[2]=a0.z; S0c[3]=a0.w;
        S0c[4]=a1.x; S0c[5]=a1.y; S0c[6]=a1.z; S0c[7]=a1.w;
        S1c[0]=b0.x; S1c[1]=b0.y; S1c[2]=b0.z; S1c[3]=b0.w;
        S1c[4]=b1.x; S1c[5]=b1.y; S1c[6]=b1.z; S1c[7]=b1.w;
        m2X[0]=-2.0f*x0.x; m2X[1]=-2.0f*x0.y; m2X[2]=-2.0f*x0.z; m2X[3]=-2.0f*x0.w;
        m2X[4]=-2.0f*x1.x; m2X[5]=-2.0f*x1.y; m2X[6]=-2.0f*x1.z; m2X[7]=-2.0f*x1.w;
        sumX = ((x0.x + x0.y) + (x0.z + x0.w)) + ((x1.x + x1.y) + (x1.z + x1.w));
    }
    const float2 hs0 = ((const float2*)(src + (size_t)j0 * ED))[lane];
    const float2 hs1 = ((const float2*)(src + (size_t)j1 * ED))[lane];

    float ea0[4], ea1[4];  // row kr handles k = i*8 + kr
    #pragma unroll
    for (int i = 0; i < 4; ++i) {
        const int k   = i * 8 + kr;
        const int jk0 = __shfl(idxreg, k, 64);
        const int jk1 = __shfl(idxreg, 32 + k, 64);
        const uint4 p0 = ((const uint4*)(PnB + ((size_t)m * NN + jk0) * DD))[d8];
        const uint4 p1 = ((const uint4*)(PnB + ((size_t)m * NN + jk1) * DD))[d8];
        const unsigned int pw0[4] = {p0.x, p0.y, p0.z, p0.w};
        const unsigned int pw1[4] = {p1.x, p1.y, p1.z, p1.w};
        float q0 = sumX, q1 = sumX;
        #pragma unroll
        for (int c = 0; c < 4; ++c) {
            const float lo0 = bflo(pw0[c]), hi0 = bfhi(pw0[c]);
            const float lo1 = bflo(pw1[c]), hi1 = bfhi(pw1[c]);
            float r;
            r = __builtin_amdgcn_rcpf(EXP2R(fmaf(lo0, C2LOG2E, S0c[c*2  ])) + 1.0f);
            q0 = fmaf(m2X[c*2  ], r, q0);
            r = __builtin_amdgcn_rcpf(EXP2R(fmaf(lo1, C2LOG2E, S1c[c*2  ])) + 1.0f);
            q1 = fmaf(m2X[c*2  ], r, q1);
            r = __builtin_amdgcn_rcpf(EXP2R(fmaf(hi0, C2LOG2E, S0c[c*2+1])) + 1.0f);
            q0 = fmaf(m2X[c*2+1], r, q0);
            r = __builtin_amdgcn_rcpf(EXP2R(fmaf(hi1, C2LOG2E, S1c[c*2+1])) + 1.0f);
            q1 = fmaf(m2X[c*2+1], r, q1);
        }
        q0 += __shfl_xor(q0, 1, 64);  q1 += __shfl_xor(q1, 1, 64);
        q0 += __shfl_xor(q0, 2, 64);  q1 += __shfl_xor(q1, 2, 64);
        q0 += __shfl_xor(q0, 4, 64);  q1 += __shfl_xor(q1, 4, 64);
        ea0[i] = q0;
        ea1[i] = q1;
    }

    // softmax x2 with the reference's full-axis baseline
    const float baseline = (m == 0) ? -1e-9f : (1.0f / (float)NN);
    float mx0 = ea0[0], mx1 = ea1[0];
    #pragma unroll
    for (int i = 1; i < 4; ++i) { mx0 = fmaxf(mx0, ea0[i]); mx1 = fmaxf(mx1, ea1[i]); }
    mx0 = fmaxf(mx0, __shfl_xor(mx0, 8, 64));
    mx1 = fmaxf(mx1, __shfl_xor(mx1, 8, 64));
    mx0 = fmaxf(mx0, __shfl_xor(mx0, 16, 64));
    mx1 = fmaxf(mx1, __shfl_xor(mx1, 16, 64));
    mx0 = fmaxf(mx0, __shfl_xor(mx0, 32, 64));
    mx1 = fmaxf(mx1, __shfl_xor(mx1, 32, 64));
    mx0 = fmaxf(mx0, baseline);
    mx1 = fmaxf(mx1, baseline);
    float sum0 = 0.0f, sum1 = 0.0f;
    #pragma unroll
    for (int i = 0; i < 4; ++i) {
        ea0[i] = __expf(ea0[i] - mx0); sum0 += ea0[i];
        ea1[i] = __expf(ea1[i] - mx1); sum1 += ea1[i];
    }
    sum0 += __shfl_xor(sum0, 8, 64);   sum1 += __shfl_xor(sum1, 8, 64);
    sum0 += __shfl_xor(sum0, 16, 64);  sum1 += __shfl_xor(sum1, 16, 64);
    sum0 += __shfl_xor(sum0, 32, 64);  sum1 += __shfl_xor(sum1, 32, 64);
    const float inv0 =
        __builtin_amdgcn_rcpf(sum0 + (float)(NN - KK) * __expf(baseline - mx0));
    const float inv1 =
        __builtin_amdgcn_rcpf(sum1 + (float)(NN - KK) * __expf(baseline - mx1));
    #pragma unroll
    for (int i = 0; i < 4; ++i) { ea0[i] *= inv0; ea1[i] *= inv1; }

    // H aggregation: lane covers elements {2*lane, 2*lane+1} of each node.
    // A for k lives in e-index k>>3 of row k&7 -> readlane (k&7)*8.
    float2 ha = hs0, hb = hs1;
    #pragma unroll
    for (int k = 0; k < KK; ++k) {
        const float a0 = readlane_f(ea0[k >> 3], (k & 7) * 8);
        const float a1 = readlane_f(ea1[k >> 3], (k & 7) * 8);
        const int  jk0 = __builtin_amdgcn_readlane(idxreg, k);
        const int  jk1 = __builtin_amdgcn_readlane(idxreg, 32 + k);
        const unsigned int o0 = ((const unsigned int*)(otherB + (size_t)jk0 * ED))[lane];
        const unsigned int o1 = ((const unsigned int*)(otherB + (size_t)jk1 * ED))[lane];
        ha.x = fmaf(a0, bflo(o0), ha.x);
        hb.x = fmaf(a1, bflo(o1), hb.x);
        ha.y = fmaf(a0, bfhi(o0), ha.y);
        hb.y = fmaf(a1, bfhi(o1), hb.y);
    }
    const unsigned int hu0 =
        (unsigned int)f2bf(ha.x) | ((unsigned int)f2bf(ha.y) << 16);
    const unsigned int hu1 =
        (unsigned int)f2bf(hb.x) | ((unsigned int)f2bf(hb.y) << 16);
    ((unsigned int*)(HoutB + ((size_t)m * NN + j0) * ED))[lane] = hu0;
    ((unsigned int*)(HoutB + ((size_t)m * NN + j1) * ED))[lane] = hu1;
}

// -------------------------------------------------------------------------
// sem_mfma: per-block beta partials, direct slot write (no atomics).
// grid: (NN/64, MM), block 256.
// -------------------------------------------------------------------------
__global__ __launch_bounds__(256) void sem_mfma(
    const unsigned short* __restrict__ HB,    // [MM,NN,ED] bf16
    const unsigned short* __restrict__ WqT,   // [MM,DD,ED] bf16
    const float* __restrict__ Bq,             // [MM,DD]
    const float* __restrict__ Qv,             // [MM,DD]
    float* __restrict__ bp)                   // [MM*128]
{
    const int m    = blockIdx.y;
    const int tid  = threadIdx.x;
    const int wave = tid >> 6;
    const int lane = tid & 63;
    const int nrow = lane & 15;
    const int quad = lane >> 4;
    const int r0   = blockIdx.x * 64 + wave * 16;

    __shared__ float red_sh[4];

    const short8* A8 = (const short8*)(HB + ((size_t)m * NN + r0 + nrow) * ED);
    const short8* B8 = (const short8*)(WqT + (size_t)m * DD * ED);

    f32x4 acc0 = {0.f, 0.f, 0.f, 0.f};
    f32x4 acc1 = {0.f, 0.f, 0.f, 0.f};
    f32x4 acc2 = {0.f, 0.f, 0.f, 0.f};
    f32x4 acc3 = {0.f, 0.f, 0.f, 0.f};

    #pragma unroll
    for (int kq = 0; kq < 4; ++kq) {
        const short8 a = A8[kq * 4 + quad];
        const short8 b0 = B8[(0 * 16 + nrow) * 16 + kq * 4 + quad];
        const short8 b1 = B8[(1 * 16 + nrow) * 16 + kq * 4 + quad];
        const short8 b2 = B8[(2 * 16 + nrow) * 16 + kq * 4 + quad];
        const short8 b3 = B8[(3 * 16 + nrow) * 16 + kq * 4 + quad];
        acc0 = __builtin_amdgcn_mfma_f32_16x16x32_bf16(a, b0, acc0, 0, 0, 0);
        acc1 = __builtin_amdgcn_mfma_f32_16x16x32_bf16(a, b1, acc1, 0, 0, 0);
        acc2 = __builtin_amdgcn_mfma_f32_16x16x32_bf16(a, b2, acc2, 0, 0, 0);
        acc3 = __builtin_amdgcn_mfma_f32_16x16x32_bf16(a, b3, acc3, 0, 0, 0);
    }

    f32x4 accs[4] = {acc0, acc1, acc2, acc3};
    float part = 0.0f;
    #pragma unroll
    for (int t = 0; t < 4; ++t) {
        const int d = t * 16 + nrow;
        const float bq = Bq[m * DD + d];
        const float qv = Qv[m * DD + d];
        #pragma unroll
        for (int reg = 0; reg < 4; ++reg)
            part = fmaf(ftanh(accs[t][reg] + bq), qv, part);
    }
    #pragma unroll
    for (int off = 32; off; off >>= 1) part += __shfl_xor(part, off, 64);
    if (lane == 0) red_sh[wave] = part;
    __syncthreads();
    if (tid == 0)
        bp[m * 128 + blockIdx.x] =
            (red_sh[0] + red_sh[1]) + (red_sh[2] + red_sh[3]);
}

// -------------------------------------------------------------------------
// combine: beta softmax from bp in-kernel (wave 0, redundant per block),
// then out = sum_m bw[m]*H[m]. grid: (NN*ED/4/256), block 256.
// -------------------------------------------------------------------------
__global__ __launch_bounds__(256) void combine_kernel(
    const unsigned short* __restrict__ HB,  // [MM,NN,ED] bf16
    const float* __restrict__ bp,           // [MM*128] partials
    float* __restrict__ outp,               // [NN,ED] f32
    unsigned short* __restrict__ outB)      // [NN,ED] bf16 or nullptr
{
    __shared__ float bw_sh[4];
    const int tid = threadIdx.x;
    if (tid < 64) {
        const int m = tid >> 4, t = tid & 15;
        float s = 0.0f;
        #pragma unroll
        for (int i = 0; i < 8; ++i)
            s += bp[m * 128 + t + i * 16];
        s += __shfl_xor(s, 1, 64);
        s += __shfl_xor(s, 2, 64);
        s += __shfl_xor(s, 4, 64);
        s += __shfl_xor(s, 8, 64);
        const float v = s * (1.0f / (float)NN);
        float mx = v;
        mx = fmaxf(mx, __shfl_xor(mx, 16, 64));
        mx = fmaxf(mx, __shfl_xor(mx, 32, 64));
        const float e = expf(v - mx);
        float es = e;
        es += __shfl_xor(es, 16, 64);
        es += __shfl_xor(es, 32, 64);
        if (t == 0) bw_sh[m] = e / es;
    }
    __syncthreads();

    const int i = blockIdx.x * 256 + tid;           // uint2 (4-elem) index
    const size_t st = (size_t)NN * ED / 4;
    const uint2* h = (const uint2*)HB;
    float r0 = 0.f, r1 = 0.f, r2 = 0.f, r3 = 0.f;
    #pragma unroll
    for (int s = 0; s < MM; ++s) {
        const float b = bw_sh[s];
        const uint2 v = h[s * st + i];
        r0 = fmaf(b, bflo(v.x), r0);
        r1 = fmaf(b, bfhi(v.x), r1);
        r2 = fmaf(b, bflo(v.y), r2);
        r3 = fmaf(b, bfhi(v.y), r3);
    }
    float4 o; o.x = r0; o.y = r1; o.z = r2; o.w = r3;
    ((float4*)outp)[i] = o;
    if (outB) {
        uint2 ob;
        ob.x = (unsigned int)f2bf(r0) | ((unsigned int)f2bf(r1) << 16);
        ob.y = (unsigned int)f2bf(r2) | ((unsigned int)f2bf(r3) << 16);
        ((uint2*)outB)[i] = ob;
    }
}

// -------------------------------------------------------------------------
extern "C" void kernel_launch(void* const* d_in, const int* in_sizes, int n_in,
                              void* d_out, int out_size, void* d_ws, size_t ws_size,
                              hipStream_t stream)
{
    // dict order: user, product, V, X, W_p, B_p, W_q, B_q, Q, user_nbrs, product_nbrs
    const float* user    = (const float*)d_in[0];
    const float* product = (const float*)d_in[1];
    const float* V   = (const float*)d_in[2];
    const float* X   = (const float*)d_in[3];
    const float* W_p = (const float*)d_in[4];
    const float* B_p = (const float*)d_in[5];
    const float* W_q = (const float*)d_in[6];
    const float* B_q = (const float*)d_in[7];
    const float* Q   = (const float*)d_in[8];
    const int* user_nbrs    = (const int*)d_in[9];
    const int* product_nbrs = (const int*)d_in[10];

    float* out  = (float*)d_out;            // [2,NN,ED] f32
    float* out0 = out;
    float* out1 = out + (size_t)NN * ED;

    // workspace layout
    float* ws = (float*)d_ws;
    float* bp = ws;                               // 512 (pad 1024)
    float* S  = bp + 1024;                        // MM*NN*DD f32
    unsigned short* us = (unsigned short*)(S + (size_t)MM * NN * DD);
    unsigned short* PnB      = us;                             // MM*NN*DD
    unsigned short* HB       = PnB + (size_t)MM * NN * DD;     // MM*NN*ED
    unsigned short* userB    = HB + (size_t)MM * NN * ED;      // NN*ED
    unsigned short* productB = userB + (size_t)NN * ED;        // NN*ED
    unsigned short* oB       = productB + (size_t)NN * ED;     // NN*ED
    unsigned short* VT       = oB + (size_t)NN * ED;           // 2*MM*DD*ED
    unsigned short* PT       = VT + (size_t)2 * MM * DD * ED;
    unsigned short* QT       = PT + (size_t)2 * MM * DD * ED;

    const size_t MED = (size_t)MM * ED * DD;   // per-phase weight slice
    const size_t MD  = (size_t)MM * DD;

    const dim3 gM2(NN / 64, MM, 2);            // fused proj grid
    const dim3 gM(NN / 64, MM);                // sem grid
    const dim3 gA(NN / 8, MM);                 // attn grid (2 nodes/wave)
    const int cBlocks = (NN * ED / 4) / 256;   // 1024

    // ---------------- prep: conversions + transposes, one launch ----------
    prep_kernel<<<dim3(1024, 5), 256, 0, stream>>>(user, userB, product, productB,
                                                   V, VT, W_p, PT, W_q, QT);

    // ===================== phase 0: user side =====================
    {
        proj2_mfma<<<gM2, 256, 0, stream>>>(userB, VT, B_p, S,
                                            productB, PT, PnB);
        attn_kernel<<<gA, 256, 0, stream>>>(user, productB, user_nbrs,
                                            S, PnB, X, HB);
        sem_mfma<<<gM, 256, 0, stream>>>(HB, QT, B_q, Q, bp);
        combine_kernel<<<cBlocks, 256, 0, stream>>>(HB, bp, out0, oB);
    }

    // ===================== phase 1: product side ==================
    // attends over the UPDATED user embeddings (= out0 / oB)
    {
        proj2_mfma<<<gM2, 256, 0, stream>>>(productB, VT + MED, B_p + MD, S,
                                            oB, PT + MED, PnB);
        attn_kernel<<<gA, 256, 0, stream>>>(product, oB, product_nbrs,
                                            S, PnB, X + MD, HB);
        sem_mfma<<<gM, 256, 0, stream>>>(HB, QT + MED, B_q + MD, Q + MD, bp);
        combine_kernel<<<cBlocks, 256, 0, stream>>>(HB, bp, out1, nullptr);
    }
}